// Round 11
// baseline (134.297 us; speedup 1.0000x reference)
//
#include <hip/hip_runtime.h>
#include <hip/hip_bf16.h>

#define T_DIM 8192
#define H_DIM 2048
#define D_DIM 1024
#define PAD_R 32          // zero lead rows of xb = scan warm-up window
#define KT    16          // K tiles of BK=64
#define USTR  164         // u-tile col stride (u16), mult of 4 for b64 align

typedef __bf16 bf16x8 __attribute__((ext_vector_type(8)));
typedef float floatx4 __attribute__((ext_vector_type(4)));
typedef unsigned short u16;

__device__ __forceinline__ u16 f2bf(float f) {
    __hip_bfloat16 b = __float2bfloat16(f);
    return *reinterpret_cast<u16*>(&b);
}
__device__ __forceinline__ float bf2f(u16 v) {
    return __uint_as_float((unsigned)v << 16);
}

#define GLDS(g, l) \
    __builtin_amdgcn_global_load_lds((const __attribute__((address_space(1))) void*)(g), \
                                     (__attribute__((address_space(3))) void*)(l), 16, 0, 0)

// ---------------------------------------------------------------------------
// fp32 -> bf16 convert: xb gets 32 leading ZERO rows (scan warm-up), then x;
// bb = B. ~63MB traffic -> ~10us at BW (measured at roofline).
// ---------------------------------------------------------------------------
__global__ __launch_bounds__(256) void conv_kernel(const float* __restrict__ x,
                                                   const float* __restrict__ Bm,
                                                   u16* __restrict__ xb,
                                                   u16* __restrict__ bb) {
    const int nPad4 = PAD_R * D_DIM / 4;
    const int nX4   = (T_DIM + PAD_R) * D_DIM / 4;
    const int nB4   = H_DIM * D_DIM / 4;
    int i = blockIdx.x * 256 + threadIdx.x;
    if (i < nX4) {
        ushort4 o;
        if (i < nPad4) {
            o.x = o.y = o.z = o.w = 0;
        } else {
            const float4 v = reinterpret_cast<const float4*>(x)[i - nPad4];
            o.x = f2bf(v.x); o.y = f2bf(v.y); o.z = f2bf(v.z); o.w = f2bf(v.w);
        }
        reinterpret_cast<ushort4*>(xb)[i] = o;
    } else {
        i -= nX4;
        if (i >= nB4) return;
        const float4 v = reinterpret_cast<const float4*>(Bm)[i];
        ushort4 o;
        o.x = f2bf(v.x); o.y = f2bf(v.y); o.z = f2bf(v.z); o.w = f2bf(v.w);
        reinterpret_cast<ushort4*>(bb)[i] = o;
    }
}

// ---------------------------------------------------------------------------
// Fused 160x128 GEMM + scan, r7 geometry (2 blocks/CU, best measured) with
// ROLE-SPLIT phases + one-tile register prefetch: every MFMA cluster is
// WAIT-FREE (its frags were lgkm-drained a phase earlier), every read burst
// runs under a wait-free MFMA cluster. r7/r9 post-mortem: all pipes <40%,
// the cost was in-phase lgkm exposure; TLP (r9) couldn't fill it.
// 256 thr = 4 waves (2M x 2N), per-wave 80x64 (acc[5][4]), BK=64, KT=16.
// LDS 73728B: A dbuf 2x[160][64] (40KB) + B dbuf 2x[128][64] (32KB) -> 2/CU.
// Pa(t): ds_read 18 frags(t) [af,b0,b1 -> E/O reg set by parity]; GLDS
//   A(t+1)x5 -> opposite A-buf; MFMA 20 = second half of tile t-1 (b1-half,
//   regs drained at Pa(t-1) lgkm(0) -> NO wait); lgkm(0) [covered by MFMA;
//   also gates Pb's B-restage]; bar.
// Pb(t): GLDS B(t+2)x4 -> same-parity B-buf (B(t) reads drained at Pa);
//   MFMA 20 = first half of tile t (b0-half, drained at Pa -> NO wait);
//   vmcnt(4) [outstanding old->new: B(t+1)4, A(t+1)5, B(t+2)4 -> keep 4 =
//   B(t+2), UNIFORM (A = 5 full units, no tid split)]; bar.
// Tail: vmcnt(0) from t=KT-2. Peel: b1-half of tile KT-1 after the loop.
// Granule-XOR swizzle (col ^= (row&7)*8) both sides -> 0 bank conflicts.
// Epilogue (r7 verbatim): u-tile col-major [128][USTR] bf16 (b64 repack),
// 2 half-scans per column (32 warm + 64 out), coalesced fp32 out.
// Register budget: 32 frags (afE/afO 10+10, b1E/b1O 4+4, b0 4) = 128 VGPR
// + acc 80 + addr ~20 => ~225, fits 2 waves/SIMD without spill (verify!).
// ---------------------------------------------------------------------------
__device__ __forceinline__ bf16x8 lds_frag(const u16* base, int row, int kx, int kseg) {
    const int cp = (kx + kseg * 8) ^ ((row & 7) * 8);
    return *reinterpret_cast<const bf16x8*>(base + row * 64 + cp);
}

#define MFMA_H(NH, BF, AF)                                                           \
    _Pragma("unroll")                                                                \
    for (int kx = 0; kx < 2; ++kx)                                                   \
        _Pragma("unroll")                                                            \
        for (int mi = 0; mi < 5; ++mi)                                               \
            _Pragma("unroll")                                                        \
            for (int nj = 0; nj < 2; ++nj)                                           \
                acc[mi][(NH) * 2 + nj] = __builtin_amdgcn_mfma_f32_16x16x32_bf16(    \
                    AF[mi][kx], BF[nj][kx], acc[mi][(NH) * 2 + nj], 0, 0, 0);

#define READ_FRAGS(CA, CB, AF, B1)                                                   \
    _Pragma("unroll")                                                                \
    for (int mi = 0; mi < 5; ++mi)                                                   \
        _Pragma("unroll")                                                            \
        for (int kx = 0; kx < 2; ++kx)                                               \
            AF[mi][kx] = lds_frag(CA, wm + mi * 16 + lrow, kx * 32, kseg);           \
    _Pragma("unroll")                                                                \
    for (int nj = 0; nj < 2; ++nj)                                                   \
        _Pragma("unroll")                                                            \
        for (int kx = 0; kx < 2; ++kx) {                                             \
            b0[nj][kx] = lds_frag(CB, wn + nj * 16 + lrow, kx * 32, kseg);           \
            B1[nj][kx] = lds_frag(CB, wn + 32 + nj * 16 + lrow, kx * 32, kseg);      \
        }

#define STAGE_A(GA1, DA)                                                             \
    _Pragma("unroll")                                                                \
    for (int u = 0; u < 5; ++u)                                                      \
        GLDS((GA1) + (size_t)(u * 32) * D_DIM, (DA) + u * 2048 + tid * 8);

#define STAGE_B(GB2, DB)                                                             \
    _Pragma("unroll")                                                                \
    for (int u = 0; u < 4; ++u)                                                      \
        GLDS((GB2) + (size_t)(u * 32) * D_DIM, (DB) + u * 2048 + tid * 8);

#define PH_BAR()    __builtin_amdgcn_s_barrier()
#define SCHEDB()    __builtin_amdgcn_sched_barrier(0)
#define LGKM0()     do { asm volatile("s_waitcnt lgkmcnt(0)" ::: "memory"); \
                         SCHEDB(); } while (0)

__global__ __launch_bounds__(256, 2) void gemm_kernel(const u16* __restrict__ xb,
                                                      const u16* __restrict__ bb,
                                                      const float* __restrict__ lam,
                                                      float* __restrict__ out) {
    __shared__ alignas(16) u16 smem[36864];   // 73728 B -> 2 blocks/CU
    u16* sA = smem;                    // 2 bufs x 10240 u16 ([160][64])
    u16* sB = smem + 20480;            // 2 bufs x  8192 u16 ([128][64])

    const int tid  = threadIdx.x;
    const int lane = tid & 63;
    const int wid  = tid >> 6;         // 0..3
    const int lrow = lane & 15;
    const int kseg = lane >> 4;
    const int wm   = (wid >> 1) * 80;
    const int wn   = (wid & 1) * 64;

    // T1: XCD-aware mapping (bijective; 1024 blocks = 8 xcd x 16 bn x 8 bm).
    const int bid = blockIdx.x;
    const int xcd = bid & 7, idx = bid >> 3;
    const int bn  = idx & 15;                  // 0..15
    const int bm  = xcd * 8 + (idx >> 4);      // 0..63

    // staging map: 256 thr * 16B = 32 rows per GLDS unit; unit offsets are
    // multiples of 32 rows -> r&7 preserved -> swizzle matches reader.
    const int rS = tid >> 3;                   // 0..31
    const int cS = ((tid & 7) * 8) ^ ((rS & 7) * 8);
    const u16* gA = xb + (size_t)(bm * 128 + rS) * D_DIM + cS;  // padded space
    const u16* gB = bb + (size_t)(bn * 128 + rS) * D_DIM + cS;

    floatx4 acc[5][4] = {};
    bf16x8 afE[5][2], afO[5][2], b1E[2][2], b1O[2][2], b0[2][2];

    // ---- prologue: A(0)x5, B(0)x4, B(1)x4. vmcnt(4): retire A(0)+B(0),
    // keep B(1)x4 in flight (uniform; no tid-split anywhere in staging).
    STAGE_A(gA, sA)
    STAGE_B(gB, sB)
    STAGE_B(gB + 64, sB + 8192)
    asm volatile("s_waitcnt vmcnt(4)" ::: "memory");
    PH_BAR();

#pragma unroll 1
    for (int p = 0; p < KT / 2; ++p) {
        const int tE = 2 * p;
        // ================= tile tE (even parity: cA=sA, cB=sB) =============
        {
            // ---- Pa(tE): read E-set; stage A(tE+1)->buf1; MFMA b1-half(prev)
            READ_FRAGS(sA, sB, afE, b1E)
            SCHEDB();
            STAGE_A(gA + (size_t)(tE + 1) * 64, sA + 10240)   // tE+1 <= 15
            SCHEDB();
            if (p > 0) {
                __builtin_amdgcn_s_setprio(1);
                MFMA_H(1, b1O, afO)        // second half of tile 2p-1
                __builtin_amdgcn_s_setprio(0);
            }
            LGKM0();
            PH_BAR();
            // ---- Pb(tE): stage B(tE+2)->buf0; MFMA b0-half(tE); vmcnt
            if (p < 7)
                STAGE_B(gB + (size_t)(tE + 2) * 64, sB)
            __builtin_amdgcn_s_setprio(1);
            MFMA_H(0, b0, afE)
            __builtin_amdgcn_s_setprio(0);
            if (p < 7) asm volatile("s_waitcnt vmcnt(4)" ::: "memory");
            else       asm volatile("s_waitcnt vmcnt(0)" ::: "memory");
            PH_BAR();
        }
        // ================= tile tE+1 (odd parity: cA=sA+10240, cB=sB+8192) ==
        {
            // ---- Pa: read O-set; stage A(tE+2)->buf0; MFMA b1-half(tE)
            READ_FRAGS(sA + 10240, sB + 8192, afO, b1O)
            SCHEDB();
            if (p < 7)
                STAGE_A(gA + (size_t)(tE + 2) * 64, sA)
            SCHEDB();
            __builtin_amdgcn_s_setprio(1);
            MFMA_H(1, b1E, afE)            // second half of tile tE
            __builtin_amdgcn_s_setprio(0);
            LGKM0();
            PH_BAR();
            // ---- Pb: stage B(tE+3)->buf1; MFMA b0-half(tE+1); vmcnt
            if (p < 7)
                STAGE_B(gB + (size_t)(tE + 3) * 64, sB + 8192)
            __builtin_amdgcn_s_setprio(1);
            MFMA_H(0, b0, afO)
            __builtin_amdgcn_s_setprio(0);
            if (p < 7) asm volatile("s_waitcnt vmcnt(4)" ::: "memory");
            else       asm volatile("s_waitcnt vmcnt(0)" ::: "memory");
            PH_BAR();
        }
    }
    // ---- peel: second half of tile KT-1 (odd set)
    __builtin_amdgcn_s_setprio(1);
    MFMA_H(1, b1O, afO)
    __builtin_amdgcn_s_setprio(0);

    // ---- epilogue 1: acc -> LDS u-tile, COLUMN-major [128][USTR] bf16.
    // Lane's 4 acc values (rows r0..r0+3 of one col) -> one ds_write_b64.
    u16* ut = smem;
#pragma unroll
    for (int mi = 0; mi < 5; ++mi)
#pragma unroll
        for (int nj = 0; nj < 4; ++nj) {
            const int col  = wn + nj * 16 + lrow;
            const int row0 = wm + mi * 16 + kseg * 4;
            ushort4 w;
            w.x = f2bf(acc[mi][nj][0]); w.y = f2bf(acc[mi][nj][1]);
            w.z = f2bf(acc[mi][nj][2]); w.w = f2bf(acc[mi][nj][3]);
            *reinterpret_cast<ushort4*>(ut + col * USTR + row0) = w;
        }
    __syncthreads();

    // ---- epilogue 2: two parallel half-scans per column (32 warm + 64 out),
    // ds_read_b64 (4 rows per read), coalesced fp32 stores.
    {
        const int half = tid >> 7;          // 0 or 1
        const int c    = tid & 127;
        const float a  = 1.0f / (1.0f + __expf(-lam[bn * 128 + c]));
        const u16* colp = ut + c * USTR;
        const int rb = half * 64;
        float h = 0.0f;
#pragma unroll
        for (int qb = 0; qb < 8; ++qb) {
            const ushort4 v = *reinterpret_cast<const ushort4*>(colp + rb + qb * 4);
            h = fmaf(a, h, bf2f(v.x)); h = fmaf(a, h, bf2f(v.y));
            h = fmaf(a, h, bf2f(v.z)); h = fmaf(a, h, bf2f(v.w));
        }
        float* op = out + (size_t)(bm * 128 + rb) * H_DIM + bn * 128 + c;
#pragma unroll 8
        for (int qb = 0; qb < 16; ++qb) {
            const ushort4 v = *reinterpret_cast<const ushort4*>(colp + rb + 32 + qb * 4);
            h = fmaf(a, h, bf2f(v.x)); op[(size_t)(qb * 4 + 0) * H_DIM] = h;
            h = fmaf(a, h, bf2f(v.y)); op[(size_t)(qb * 4 + 1) * H_DIM] = h;
            h = fmaf(a, h, bf2f(v.z)); op[(size_t)(qb * 4 + 2) * H_DIM] = h;
            h = fmaf(a, h, bf2f(v.w)); op[(size_t)(qb * 4 + 3) * H_DIM] = h;
        }
    }
}

// ---------------------------------------------------------------------------
extern "C" void kernel_launch(void* const* d_in, const int* in_sizes, int n_in,
                              void* d_out, int out_size, void* d_ws, size_t ws_size,
                              hipStream_t stream) {
    const float* x   = (const float*)d_in[0];   // [T, D]
    const float* lam = (const float*)d_in[1];   // [H]
    const float* B   = (const float*)d_in[2];   // [H, D]
    float* out = (float*)d_out;                 // [T, H]

    // ws: xb [T+32][D] bf16 (16.9MB) + bb [H][D] bf16 (4.2MB) = 21MB.
    u16* xb = (u16*)d_ws;
    u16* bb = xb + (size_t)(T_DIM + PAD_R) * D_DIM;

    const int n4 = ((T_DIM + PAD_R) * D_DIM + H_DIM * D_DIM) / 4;
    conv_kernel<<<(n4 + 255) / 256, 256, 0, stream>>>(x, B, xb, bb);
    gemm_kernel<<<(H_DIM / 128) * (T_DIM / 128), 256, 0, stream>>>(xb, bb, lam, out);
}